// Round 11
// baseline (88.352 us; speedup 1.0000x reference)
//
#include <hip/hip_runtime.h>
#include <math.h>

#define HX 48
#define WX 48
#define OMC 216
#define HY 96
#define WY 96

typedef __attribute__((ext_vector_type(8))) short bf16x8;
typedef __attribute__((ext_vector_type(4))) float f32x4;

__device__ inline unsigned short f2bf(float f) {
  unsigned u = __float_as_uint(f);
  return (unsigned short)((u + 0x7fffu + ((u >> 16) & 1u)) >> 16);  // RNE
}
__device__ inline unsigned pk2(float a, float b) {
  return (unsigned)f2bf(a) | ((unsigned)f2bf(b) << 16);
}

// wave-level sync: order LDS writes->reads within a wave, no block barrier
#define WAVE_SYNC()                                         \
  do {                                                      \
    asm volatile("s_waitcnt lgkmcnt(0)" ::: "memory");      \
    __builtin_amdgcn_wave_barrier();                        \
  } while (0)

// ws layout (floats):
//  om  @ 0          : 1,990,656
//  ap2 @ 1,990,656  :    73,728   (147,456 bf16)
//  ap1 @ 2,064,384  :    18,432   ( 36,864 bf16)
//  yt  @ 2,082,816  : 2,359,296
//  rs  @ 4,442,112  : 7,962,624   ([b][k][g][px9216][3] = py,px,m interleaved)

// ---------- fused: prep (blocks 0..719) + ytr (blocks 720..1295) ----------
__global__ __launch_bounds__(256) void prep_ytr_kernel(
    const float* __restrict__ w_om, const float* __restrict__ w_dc,
    const float* __restrict__ y,
    unsigned short* __restrict__ ap2, unsigned short* __restrict__ ap1,
    float* __restrict__ yt) {
  __shared__ float tile[64][65];
  int bid = blockIdx.x;
  int t = threadIdx.x;
  if (bid < 720) {
    int idx = bid * 256 + t;                  // 0..184319
    if (idx < 147456) {
      int j = idx & 7;
      int tmp = idx >> 3;
      int l = tmp & 63; tmp >>= 6;
      int m = tmp & 15; tmp >>= 4;            // 0..17
      int s = tmp % 6, p = tmp / 6;
      int oc = m * 16 + (l & 15);
      int kk = s * 32 + (l >> 4) * 8 + j;     // 0..191
      int tap = kk >> 6, c = kk & 63;
      int k = p * 3 + tap;
      ap2[idx] = (oc < OMC) ? f2bf(w_om[oc * 576 + c * 9 + k]) : (unsigned short)0;
    } else {
      int i2 = idx - 147456;                  // < 36864
      int j = i2 & 7;
      int tmp = i2 >> 3;
      int l = tmp & 63; tmp >>= 6;
      int w = tmp & 3; tmp >>= 2;             // 0..17
      int s = tmp % 6, p = tmp / 6;
      int oc = w * 16 + (l & 15);
      int kk = s * 32 + (l >> 4) * 8 + j;
      int tap = kk >> 6, c = kk & 63;
      ap1[i2] = f2bf(w_dc[oc * 576 + c * 9 + p * 3 + tap]);
    }
  } else {
    int blk = bid - 720;                      // 576 = 4b * 144
    int b = blk / 144;
    int p0 = (blk % 144) * 64;
    int pl = t & 63;
    int cb = t >> 6;
#pragma unroll
    for (int i = 0; i < 16; ++i) {
      int c = cb * 16 + i;
      tile[c][pl] = y[((size_t)(b * 64 + c)) * 9216 + p0 + pl];
    }
    __syncthreads();
    int cw = t & 63;
    int pb = t >> 6;
#pragma unroll
    for (int i = 0; i < 16; ++i) {
      int p = pb * 16 + i;
      yt[((size_t)(b * 9216 + p0 + p)) * 64 + cw] = tile[cw][p];
    }
  }
}

// ---------- conv (9 taps) via MFMA, oc-split: 128oc x 16px per block ----------
__global__ __launch_bounds__(256) void conv_mfma_kernel(
    const float* __restrict__ x, const unsigned short* __restrict__ ap2,
    const float* __restrict__ bom, float* __restrict__ om) {
  __shared__ unsigned short sB[9][16][72];    // 20736 B, [tap][px][c]
  int t = threadIdx.x;
  int bid = blockIdx.x;                       // 1152
  int logical = (bid & 7) * 144 + (bid >> 3); // bijective XCD swizzle
  int och = logical / 576;                    // oc half
  int rem = logical % 576;
  int b = rem / 144;
  int tl = rem % 144;
  int h0 = (tl / 12) * 4;
  int w0 = (tl % 12) * 4;
  int s_ic = t >> 2;
  int s_row = t & 3;
  const float* xp = x + (size_t)b * 64 * 2304 + (size_t)s_ic * 2304;

#pragma unroll
  for (int k = 0; k < 9; ++k) {
    int dy = k / 3 - 1, dx = k % 3 - 1;
    int hh = h0 + s_row + dy;
    int ww = w0 + dx;
    bool hv = (unsigned)hh < (unsigned)HX;
    int hc = min(max(hh, 0), HX - 1);
    const float* xr = xp + hc * WX;
#pragma unroll
    for (int j = 0; j < 4; ++j) {
      int wcj = min(max(ww + j, 0), WX - 1);
      float v = xr[wcj] * ((hv && (unsigned)(ww + j) < (unsigned)WX) ? 1.f : 0.f);
      sB[k][s_row * 4 + j][s_ic] = f2bf(v);
    }
  }
  __syncthreads();

  int w = t >> 6;
  int l = t & 63;
  int lr = l & 15;
  int lg = l >> 4;
  f32x4 acc[2] = {};
#pragma unroll
  for (int p = 0; p < 3; ++p) {
#pragma unroll
    for (int s = 0; s < 6; ++s) {
      int tapidx = p * 3 + (s >> 1);
      int c0 = (s & 1) * 32;
      bf16x8 bv = *(const bf16x8*)&sB[tapidx][lr][c0 + lg * 8];
#pragma unroll
      for (int m = 0; m < 2; ++m) {
        int mq = och * 8 + w * 2 + m;         // 0..15
        bf16x8 av = *(const bf16x8*)(ap2 +
            (size_t)((((p * 6 + s) * 16) + mq) * 64 + l) * 8);
        acc[m] = __builtin_amdgcn_mfma_f32_16x16x32_bf16(av, bv, acc[m], 0, 0, 0);
      }
    }
  }
  int prow = lr >> 2, pcol = lr & 3;
#pragma unroll
  for (int m = 0; m < 2; ++m) {
    int ocb = (och * 8 + w * 2 + m) * 16 + lg * 4;
    if (ocb < OMC) {
      float4 bb = *(const float4*)&bom[ocb];
      float bvv[4] = {bb.x, bb.y, bb.z, bb.w};
#pragma unroll
      for (int i = 0; i < 4; ++i) {
        om[((size_t)(b * OMC + ocb + i)) * 2304 + (h0 + prow) * WX + w0 + pcol] =
            acc[m][i] + bvv[i];
      }
    }
  }
}

// ---------- resize: 4-way px split, stage only 14 src rows ----------
__global__ __launch_bounds__(256) void resize_kernel(const float* __restrict__ om,
                                                     float* __restrict__ rs) {
  __shared__ float sR[3][14][48];             // 8064 B
  int bid = blockIdx.x;                       // 1152 = 288 * 4
  int q = bid & 3;
  int grp = bid >> 2;                         // 0..287 = b*72 + k*8 + g
  int g = grp % 8;
  int k = (grp / 8) % 9;
  int b = grp / 72;
  const float* omb = om + (size_t)b * OMC * 2304;
  const float* s0 = omb + (size_t)(g * 18 + k * 2) * 2304;
  const float* s1 = s0 + 2304;
  const float* s2 = omb + (size_t)(144 + g * 9 + k) * 2304;
  int base = 12 * q - 1;
  for (int i = threadIdx.x; i < 504; i += 256) {    // 3ch * 14row * 12 f4
    int ch = i / 168;
    int r = (i % 168) / 12;
    int c4 = i % 12;
    int srow = min(max(base + r, 0), HX - 1);
    const float* src = (ch == 0) ? s0 : ((ch == 1) ? s1 : s2);
    *(float4*)&sR[ch][r][c4 * 4] = *(const float4*)&src[srow * 48 + c4 * 4];
  }
  __syncthreads();
  int dy = k / 3 - 1, dx = k % 3 - 1;
  float* o = rs + (size_t)((b * 9 + k) * 8 + g) * 9216 * 3;
  for (int pxl = threadIdx.x; pxl < 2304; pxl += 256) {
    int h = q * 24 + (pxl / 96);
    int w = pxl % 96;
    float sh = fmaxf(h * 0.5f - 0.25f, 0.f);
    float sw = fmaxf(w * 0.5f - 0.25f, 0.f);
    int i0h = (int)sh; float th = sh - (float)i0h;
    int i0w = (int)sw; float tw = sw - (float)i0w;
    int i1h = min(i0h + 1, HX - 1);
    int i1w = min(i0w + 1, WX - 1);
    int l0 = i0h - base, l1 = i1h - base;
    float r00 = (1.f - th) * (1.f - tw), r01 = (1.f - th) * tw;
    float r10 = th * (1.f - tw),         r11 = th * tw;
    float oy = r00 * sR[0][l0][i0w] + r01 * sR[0][l0][i1w] +
               r10 * sR[0][l1][i0w] + r11 * sR[0][l1][i1w];
    float ox = r00 * sR[1][l0][i0w] + r01 * sR[1][l0][i1w] +
               r10 * sR[1][l1][i0w] + r11 * sR[1][l1][i1w];
    float mv = r00 * sR[2][l0][i0w] + r01 * sR[2][l0][i1w] +
               r10 * sR[2][l1][i0w] + r11 * sR[2][l1][i1w];
    float mm = 1.f / (1.f + __expf(-mv));
    int pxg = h * 96 + w;
    o[pxg * 3 + 0] = (float)(h + dy) + oy;
    o[pxg * 3 + 1] = (float)(w + dx) + ox;
    o[pxg * 3 + 2] = mm;
  }
}

// ---------- deform: wave-synchronous, 8px x 64oc per wave, no block barriers ----
// NOTE: 3rd macro param must NOT be named w/x/y/z/s/d — member-access capture!
#define MAD4(d, s, mw)                                                  \
  d.x += (mw) * s.x; d.y += (mw) * s.y; d.z += (mw) * s.z; d.w += (mw) * s.w;

__global__ __launch_bounds__(256) void deform_mfma_kernel(
    const float* __restrict__ yt, const float* __restrict__ rs,
    const unsigned short* __restrict__ ap1, const float* __restrict__ bdc,
    float* __restrict__ out) {
  __shared__ unsigned short sval[4][2][8][72];  // 9216 B, wave-private [wv]
  int t = threadIdx.x;
  int bid = blockIdx.x;                         // 1152
  int logical = (bid & 7) * 144 + (bid >> 3);   // bijective XCD swizzle
  int b = logical / 288;
  int tl = logical % 288;
  int h0 = (tl / 12) * 4;                       // 24 h-tiles of 4 rows
  int w0 = (tl % 12) * 8;                       // 12 w-tiles of 8 cols
  int wv = t >> 6;
  int l = t & 63;
  // gather role: lane handles items (g0, px, cp) and (g0+4, px, cp)
  int px = (l >> 1) & 7;
  int cp = l & 1;
  int g0 = l >> 4;
  int gh = h0 + wv;                             // wave wv owns row wv of tile
  int gw = w0 + px;
  int px96 = gh * WY + gw;
  const float* ytb = yt + (size_t)b * 9216 * 64;
  const float* rsb = rs + (size_t)b * 9 * 8 * 9216 * 3;
  // MFMA role
  int lr = l & 15;
  int lg = l >> 4;

  auto issue = [&](int tap, int gsel, float4* Co, float* wo) {
    int g = g0 + gsel * 4;
    int chb = g * 8 + cp * 4;
    const float* r0 = rsb + ((size_t)(tap * 8 + g) * 9216 + px96) * 3;
    float py = r0[0], pxf = r0[1], m = r0[2];
    float y0f = floorf(py), x0f = floorf(pxf);
    float ty = py - y0f, tx = pxf - x0f;
    int y0 = (int)y0f, x0 = (int)x0f;
    int y1 = y0 + 1, x1 = x0 + 1;
    float w00 = (1.f - ty) * (1.f - tx) * m, w01 = (1.f - ty) * tx * m;
    float w10 = ty * (1.f - tx) * m,         w11 = ty * tx * m;
    wo[0] = ((unsigned)y0 < HY && (unsigned)x0 < WY) ? w00 : 0.f;
    wo[1] = ((unsigned)y0 < HY && (unsigned)x1 < WY) ? w01 : 0.f;
    wo[2] = ((unsigned)y1 < HY && (unsigned)x0 < WY) ? w10 : 0.f;
    wo[3] = ((unsigned)y1 < HY && (unsigned)x1 < WY) ? w11 : 0.f;
    int y0c = min(max(y0, 0), HY - 1), y1c = min(max(y1, 0), HY - 1);
    int x0c = min(max(x0, 0), WY - 1), x1c = min(max(x1, 0), WY - 1);
    Co[0] = *(const float4*)(ytb + (size_t)(y0c * WY + x0c) * 64 + chb);
    Co[1] = *(const float4*)(ytb + (size_t)(y0c * WY + x1c) * 64 + chb);
    Co[2] = *(const float4*)(ytb + (size_t)(y1c * WY + x0c) * 64 + chb);
    Co[3] = *(const float4*)(ytb + (size_t)(y1c * WY + x1c) * 64 + chb);
  };
  auto finish = [&](int gsel, const float4* Ci, const float* wi, int buf) {
    int chb = (g0 + gsel * 4) * 8 + cp * 4;
    float4 s0 = {0, 0, 0, 0};
    MAD4(s0, Ci[0], wi[0]) MAD4(s0, Ci[1], wi[1])
    MAD4(s0, Ci[2], wi[2]) MAD4(s0, Ci[3], wi[3])
    *(uint2*)&sval[wv][buf][px][chb] = make_uint2(pk2(s0.x, s0.y), pk2(s0.z, s0.w));
  };

  {
    float4 CA[4], CB[4];
    float WA[4], WB[4];
    issue(0, 0, CA, WA);
    issue(0, 1, CB, WB);
    finish(0, CA, WA, 0);
    finish(1, CB, WB, 0);
  }
  WAVE_SYNC();

  f32x4 acc[4] = {};
#pragma unroll
  for (int tp = 0; tp < 9; ++tp) {
    int buf = tp & 1;
    float4 C2a[4], C2b[4];
    float W2a[4], W2b[4];
    if (tp < 8) {                     // next-tap loads in flight over MFMA
      issue(tp + 1, 0, C2a, W2a);
      issue(tp + 1, 1, C2b, W2b);
    }
    int p = tp / 3;
    int sl = (tp % 3) * 2;
#pragma unroll
    for (int half = 0; half < 2; ++half) {
      int s = sl + half;
      bf16x8 bv = *(const bf16x8*)&sval[wv][buf][lr & 7][half * 32 + lg * 8];
#pragma unroll
      for (int m = 0; m < 4; ++m) {
        bf16x8 av = *(const bf16x8*)(ap1 +
            (size_t)(((p * 6 + s) * 4 + m) * 64 + l) * 8);
        acc[m] = __builtin_amdgcn_mfma_f32_16x16x32_bf16(av, bv, acc[m], 0, 0, 0);
      }
    }
    if (tp < 8) {
      finish(0, C2a, W2a, buf ^ 1);
      finish(1, C2b, W2b, buf ^ 1);
    }
    WAVE_SYNC();
  }

  // epilogue: lanes with col<8 store 64oc x 8px strip (row gh, cols w0..w0+7)
  if (lr < 8) {
#pragma unroll
    for (int m = 0; m < 4; ++m) {
      float4 bb = *(const float4*)&bdc[m * 16 + lg * 4];
      float bvv[4] = {bb.x, bb.y, bb.z, bb.w};
#pragma unroll
      for (int i = 0; i < 4; ++i) {
        int oc = m * 16 + lg * 4 + i;
        out[((size_t)(b * 64 + oc) * 96 + gh) * 96 + w0 + lr] =
            fmaxf(acc[m][i] + bvv[i], 0.f);
      }
    }
  }
}

extern "C" void kernel_launch(void* const* d_in, const int* in_sizes, int n_in,
                              void* d_out, int out_size, void* d_ws, size_t ws_size,
                              hipStream_t stream) {
  const float* x = (const float*)d_in[0];
  const float* y = (const float*)d_in[1];
  const float* w_om = (const float*)d_in[2];
  const float* b_om = (const float*)d_in[3];
  const float* w_dc = (const float*)d_in[4];
  const float* b_dc = (const float*)d_in[5];
  float* out = (float*)d_out;

  float* om  = (float*)d_ws;                       // 1,990,656 f
  unsigned short* ap2 = (unsigned short*)(om + 1990656);   // 147,456 bf16
  unsigned short* ap1 = ap2 + 147456;              //  36,864 bf16
  float* yt  = (float*)(ap1 + 36864);              // 2,359,296 f
  float* rs  = yt + 2359296;                       // 7,962,624 f

  prep_ytr_kernel<<<1296, 256, 0, stream>>>(w_om, w_dc, y, ap2, ap1, yt);
  conv_mfma_kernel<<<1152, 256, 0, stream>>>(x, ap2, b_om, om);
  resize_kernel<<<1152, 256, 0, stream>>>(om, rs);
  deform_mfma_kernel<<<1152, 256, 0, stream>>>(yt, rs, ap1, b_dc, out);
}

// Round 12
// 80.522 us; speedup vs baseline: 1.0972x; 1.0972x over previous
//
#include <hip/hip_runtime.h>
#include <math.h>

#define HX 48
#define WX 48
#define OMC 216
#define HY 96
#define WY 96

typedef __attribute__((ext_vector_type(8))) short bf16x8;
typedef __attribute__((ext_vector_type(4))) float f32x4;

__device__ inline unsigned short f2bf(float f) {
  unsigned u = __float_as_uint(f);
  return (unsigned short)((u + 0x7fffu + ((u >> 16) & 1u)) >> 16);  // RNE
}
__device__ inline unsigned pk2(float a, float b) {
  return (unsigned)f2bf(a) | ((unsigned)f2bf(b) << 16);
}

// ws layout (floats):
//  om  @ 0          : 1,990,656
//  ap2 @ 1,990,656  :    73,728   (147,456 bf16)
//  ap1 @ 2,064,384  :    18,432   ( 36,864 bf16)
//  yt  @ 2,082,816  : 2,359,296
//  rs  @ 4,442,112  : 7,962,624   ([b][k][g][px9216][3] = py,px,m interleaved)

// ---------- fused: prep (blocks 0..719) + ytr (blocks 720..1295) ----------
__global__ __launch_bounds__(256) void prep_ytr_kernel(
    const float* __restrict__ w_om, const float* __restrict__ w_dc,
    const float* __restrict__ y,
    unsigned short* __restrict__ ap2, unsigned short* __restrict__ ap1,
    float* __restrict__ yt) {
  __shared__ float tile[64][65];
  int bid = blockIdx.x;
  int t = threadIdx.x;
  if (bid < 720) {
    int idx = bid * 256 + t;                  // 0..184319
    if (idx < 147456) {
      int j = idx & 7;
      int tmp = idx >> 3;
      int l = tmp & 63; tmp >>= 6;
      int m = tmp & 15; tmp >>= 4;            // 0..17
      int s = tmp % 6, p = tmp / 6;
      int oc = m * 16 + (l & 15);
      int kk = s * 32 + (l >> 4) * 8 + j;     // 0..191
      int tap = kk >> 6, c = kk & 63;
      int k = p * 3 + tap;
      ap2[idx] = (oc < OMC) ? f2bf(w_om[oc * 576 + c * 9 + k]) : (unsigned short)0;
    } else {
      int i2 = idx - 147456;                  // < 36864
      int j = i2 & 7;
      int tmp = i2 >> 3;
      int l = tmp & 63; tmp >>= 6;
      int w = tmp & 3; tmp >>= 2;             // 0..17
      int s = tmp % 6, p = tmp / 6;
      int oc = w * 16 + (l & 15);
      int kk = s * 32 + (l >> 4) * 8 + j;
      int tap = kk >> 6, c = kk & 63;
      ap1[i2] = f2bf(w_dc[oc * 576 + c * 9 + p * 3 + tap]);
    }
  } else {
    int blk = bid - 720;                      // 576 = 4b * 144
    int b = blk / 144;
    int p0 = (blk % 144) * 64;
    int pl = t & 63;
    int cb = t >> 6;
#pragma unroll
    for (int i = 0; i < 16; ++i) {
      int c = cb * 16 + i;
      tile[c][pl] = y[((size_t)(b * 64 + c)) * 9216 + p0 + pl];
    }
    __syncthreads();
    int cw = t & 63;
    int pb = t >> 6;
#pragma unroll
    for (int i = 0; i < 16; ++i) {
      int p = pb * 16 + i;
      yt[((size_t)(b * 9216 + p0 + p)) * 64 + cw] = tile[cw][p];
    }
  }
}

// ---------- conv (9 taps) via MFMA, oc-split: 128oc x 16px per block ----------
__global__ __launch_bounds__(256) void conv_mfma_kernel(
    const float* __restrict__ x, const unsigned short* __restrict__ ap2,
    const float* __restrict__ bom, float* __restrict__ om) {
  __shared__ unsigned short sB[9][16][72];    // 20736 B, [tap][px][c]
  int t = threadIdx.x;
  int bid = blockIdx.x;                       // 1152
  int logical = (bid & 7) * 144 + (bid >> 3); // bijective XCD swizzle
  int och = logical / 576;                    // oc half
  int rem = logical % 576;
  int b = rem / 144;
  int tl = rem % 144;
  int h0 = (tl / 12) * 4;
  int w0 = (tl % 12) * 4;
  int s_ic = t >> 2;
  int s_row = t & 3;
  const float* xp = x + (size_t)b * 64 * 2304 + (size_t)s_ic * 2304;

#pragma unroll
  for (int k = 0; k < 9; ++k) {
    int dy = k / 3 - 1, dx = k % 3 - 1;
    int hh = h0 + s_row + dy;
    int ww = w0 + dx;
    bool hv = (unsigned)hh < (unsigned)HX;
    int hc = min(max(hh, 0), HX - 1);
    const float* xr = xp + hc * WX;
#pragma unroll
    for (int j = 0; j < 4; ++j) {
      int wcj = min(max(ww + j, 0), WX - 1);
      float v = xr[wcj] * ((hv && (unsigned)(ww + j) < (unsigned)WX) ? 1.f : 0.f);
      sB[k][s_row * 4 + j][s_ic] = f2bf(v);
    }
  }
  __syncthreads();

  int w = t >> 6;
  int l = t & 63;
  int lr = l & 15;
  int lg = l >> 4;
  f32x4 acc[2] = {};
#pragma unroll
  for (int p = 0; p < 3; ++p) {
#pragma unroll
    for (int s = 0; s < 6; ++s) {
      int tapidx = p * 3 + (s >> 1);
      int c0 = (s & 1) * 32;
      bf16x8 bv = *(const bf16x8*)&sB[tapidx][lr][c0 + lg * 8];
#pragma unroll
      for (int m = 0; m < 2; ++m) {
        int mq = och * 8 + w * 2 + m;         // 0..15
        bf16x8 av = *(const bf16x8*)(ap2 +
            (size_t)((((p * 6 + s) * 16) + mq) * 64 + l) * 8);
        acc[m] = __builtin_amdgcn_mfma_f32_16x16x32_bf16(av, bv, acc[m], 0, 0, 0);
      }
    }
  }
  int prow = lr >> 2, pcol = lr & 3;
#pragma unroll
  for (int m = 0; m < 2; ++m) {
    int ocb = (och * 8 + w * 2 + m) * 16 + lg * 4;
    if (ocb < OMC) {
      float4 bb = *(const float4*)&bom[ocb];
      float bvv[4] = {bb.x, bb.y, bb.z, bb.w};
#pragma unroll
      for (int i = 0; i < 4; ++i) {
        om[((size_t)(b * OMC + ocb + i)) * 2304 + (h0 + prow) * WX + w0 + pcol] =
            acc[m][i] + bvv[i];
      }
    }
  }
}

// ---------- resize: 4-way px split, stage only 14 src rows ----------
__global__ __launch_bounds__(256) void resize_kernel(const float* __restrict__ om,
                                                     float* __restrict__ rs) {
  __shared__ float sR[3][14][48];             // 8064 B
  int bid = blockIdx.x;                       // 1152 = 288 * 4
  int q = bid & 3;
  int grp = bid >> 2;                         // 0..287 = b*72 + k*8 + g
  int g = grp % 8;
  int k = (grp / 8) % 9;
  int b = grp / 72;
  const float* omb = om + (size_t)b * OMC * 2304;
  const float* s0 = omb + (size_t)(g * 18 + k * 2) * 2304;
  const float* s1 = s0 + 2304;
  const float* s2 = omb + (size_t)(144 + g * 9 + k) * 2304;
  int base = 12 * q - 1;
  for (int i = threadIdx.x; i < 504; i += 256) {    // 3ch * 14row * 12 f4
    int ch = i / 168;
    int r = (i % 168) / 12;
    int c4 = i % 12;
    int srow = min(max(base + r, 0), HX - 1);
    const float* src = (ch == 0) ? s0 : ((ch == 1) ? s1 : s2);
    *(float4*)&sR[ch][r][c4 * 4] = *(const float4*)&src[srow * 48 + c4 * 4];
  }
  __syncthreads();
  int dy = k / 3 - 1, dx = k % 3 - 1;
  float* o = rs + (size_t)((b * 9 + k) * 8 + g) * 9216 * 3;
  for (int pxl = threadIdx.x; pxl < 2304; pxl += 256) {
    int h = q * 24 + (pxl / 96);
    int w = pxl % 96;
    float sh = fmaxf(h * 0.5f - 0.25f, 0.f);
    float sw = fmaxf(w * 0.5f - 0.25f, 0.f);
    int i0h = (int)sh; float th = sh - (float)i0h;
    int i0w = (int)sw; float tw = sw - (float)i0w;
    int i1h = min(i0h + 1, HX - 1);
    int i1w = min(i0w + 1, WX - 1);
    int l0 = i0h - base, l1 = i1h - base;
    float r00 = (1.f - th) * (1.f - tw), r01 = (1.f - th) * tw;
    float r10 = th * (1.f - tw),         r11 = th * tw;
    float oy = r00 * sR[0][l0][i0w] + r01 * sR[0][l0][i1w] +
               r10 * sR[0][l1][i0w] + r11 * sR[0][l1][i1w];
    float ox = r00 * sR[1][l0][i0w] + r01 * sR[1][l0][i1w] +
               r10 * sR[1][l1][i0w] + r11 * sR[1][l1][i1w];
    float mv = r00 * sR[2][l0][i0w] + r01 * sR[2][l0][i1w] +
               r10 * sR[2][l1][i0w] + r11 * sR[2][l1][i1w];
    float mm = 1.f / (1.f + __expf(-mv));
    int pxg = h * 96 + w;
    o[pxg * 3 + 0] = (float)(h + dy) + oy;
    o[pxg * 3 + 1] = (float)(w + dx) + ox;
    o[pxg * 3 + 2] = mm;
  }
}

// ---------- deform: 16px x 64oc per block, 3-stage software pipeline ----------
// NOTE: 3rd macro param must NOT be named w/x/y/z/s/d — member-access capture!
#define MAD4(d, s, mw)                                                  \
  d.x += (mw) * s.x; d.y += (mw) * s.y; d.z += (mw) * s.z; d.w += (mw) * s.w;

__global__ __launch_bounds__(256) void deform_mfma_kernel(
    const float* __restrict__ yt, const float* __restrict__ rs,
    const unsigned short* __restrict__ ap1, const float* __restrict__ bdc,
    float* __restrict__ out) {
  __shared__ unsigned short sval[2][16][72];    // 4608 B
  int t = threadIdx.x;
  int bid = blockIdx.x;                         // 2304
  int logical = (bid & 7) * 288 + (bid >> 3);   // bijective XCD swizzle
  int b = logical / 576;
  int tl = logical % 576;
  int h0 = (tl / 24) * 4;                       // 24 h-tiles of 4
  int w0 = (tl % 24) * 4;                       // 24 w-tiles of 4

  int item = t >> 1;                            // 0..127 = g*16 + px
  int g = item >> 4;
  int px = item & 15;
  int cp = t & 1;                               // channel half of the 8-ch group
  int gh = h0 + (px >> 2);
  int gw = w0 + (px & 3);
  int px96 = gh * WY + gw;
  int chb = g * 8 + cp * 4;
  const float* ytb = yt + (size_t)b * 9216 * 64;
  const float* rsb = rs + (size_t)b * 9 * 8 * 9216 * 3;

  int w = t >> 6;
  int l = t & 63;
  int lr = l & 15;
  int lg = l >> 4;

  // pipeline state (all indices compile-time under full unroll)
  float R[3][3];      // rs triples, slot tap%3 (holds taps tp+1..tp+3)
  float4 C[2][4];     // corner loads, slot tap&1
  float W[2][4];      // corner weights, slot tap&1

  auto loadR = [&](int tap, float* Ro) {
    const float* r0 = rsb + ((size_t)(tap * 8 + g) * 9216 + px96) * 3;
    Ro[0] = r0[0]; Ro[1] = r0[1]; Ro[2] = r0[2];
  };
  auto issueC = [&](const float* Ri, float4* Co, float* Wo) {
    float py = Ri[0], pxf = Ri[1], m = Ri[2];
    float y0f = floorf(py), x0f = floorf(pxf);
    float ty = py - y0f, tx = pxf - x0f;
    int y0 = (int)y0f, x0 = (int)x0f;
    int y1 = y0 + 1, x1 = x0 + 1;
    float w00 = (1.f - ty) * (1.f - tx) * m, w01 = (1.f - ty) * tx * m;
    float w10 = ty * (1.f - tx) * m,         w11 = ty * tx * m;
    Wo[0] = ((unsigned)y0 < HY && (unsigned)x0 < WY) ? w00 : 0.f;
    Wo[1] = ((unsigned)y0 < HY && (unsigned)x1 < WY) ? w01 : 0.f;
    Wo[2] = ((unsigned)y1 < HY && (unsigned)x0 < WY) ? w10 : 0.f;
    Wo[3] = ((unsigned)y1 < HY && (unsigned)x1 < WY) ? w11 : 0.f;
    int y0c = min(max(y0, 0), HY - 1), y1c = min(max(y1, 0), HY - 1);
    int x0c = min(max(x0, 0), WY - 1), x1c = min(max(x1, 0), WY - 1);
    Co[0] = *(const float4*)(ytb + (size_t)(y0c * WY + x0c) * 64 + chb);
    Co[1] = *(const float4*)(ytb + (size_t)(y0c * WY + x1c) * 64 + chb);
    Co[2] = *(const float4*)(ytb + (size_t)(y1c * WY + x0c) * 64 + chb);
    Co[3] = *(const float4*)(ytb + (size_t)(y1c * WY + x1c) * 64 + chb);
  };
  auto finishC = [&](const float4* Ci, const float* Wi, int buf) {
    float4 s0 = {0, 0, 0, 0};
    MAD4(s0, Ci[0], Wi[0]) MAD4(s0, Ci[1], Wi[1])
    MAD4(s0, Ci[2], Wi[2]) MAD4(s0, Ci[3], Wi[3])
    *(uint2*)&sval[buf][px][chb] = make_uint2(pk2(s0.x, s0.y), pk2(s0.z, s0.w));
  };

  // prologue: R0, R1, C0 (from R0), R2
  loadR(0, R[0]);
  loadR(1, R[1]);
  issueC(R[0], C[0], W[0]);
  loadR(2, R[2]);

  f32x4 acc = {};
#pragma unroll
  for (int tp = 0; tp < 9; ++tp) {
    if (tp + 3 < 9) loadR(tp + 3, R[(tp + 3) % 3]);          // 2-iter flight
    if (tp + 1 < 9) issueC(R[(tp + 1) % 3], C[(tp + 1) & 1], W[(tp + 1) & 1]);  // 1-iter flight
    finishC(C[tp & 1], W[tp & 1], tp & 1);                   // issued last iter
    __syncthreads();
    int p = tp / 3;
    int sl = (tp % 3) * 2;
#pragma unroll
    for (int half = 0; half < 2; ++half) {
      int s = sl + half;
      bf16x8 av = *(const bf16x8*)(ap1 +
          (size_t)(((p * 6 + s) * 4 + w) * 64 + l) * 8);
      bf16x8 bv = *(const bf16x8*)&sval[tp & 1][lr][half * 32 + lg * 8];
      acc = __builtin_amdgcn_mfma_f32_16x16x32_bf16(av, bv, acc, 0, 0, 0);
    }
    // no second barrier: finishC[tp+2] (same buf) is fenced by barrier[tp+1],
    // which program-order follows this MFMA on every wave.
  }

  // epilogue: bias + relu + store (oc = w*16+lg*4+i, px = lr in 4x4 tile)
  float4 bb = *(const float4*)&bdc[w * 16 + lg * 4];
  float bvv[4] = {bb.x, bb.y, bb.z, bb.w};
#pragma unroll
  for (int i = 0; i < 4; ++i) {
    int oc = w * 16 + lg * 4 + i;
    out[((size_t)(b * 64 + oc) * 96 + h0 + (lr >> 2)) * 96 + w0 + (lr & 3)] =
        fmaxf(acc[i] + bvv[i], 0.f);
  }
}

extern "C" void kernel_launch(void* const* d_in, const int* in_sizes, int n_in,
                              void* d_out, int out_size, void* d_ws, size_t ws_size,
                              hipStream_t stream) {
  const float* x = (const float*)d_in[0];
  const float* y = (const float*)d_in[1];
  const float* w_om = (const float*)d_in[2];
  const float* b_om = (const float*)d_in[3];
  const float* w_dc = (const float*)d_in[4];
  const float* b_dc = (const float*)d_in[5];
  float* out = (float*)d_out;

  float* om  = (float*)d_ws;                       // 1,990,656 f
  unsigned short* ap2 = (unsigned short*)(om + 1990656);   // 147,456 bf16
  unsigned short* ap1 = ap2 + 147456;              //  36,864 bf16
  float* yt  = (float*)(ap1 + 36864);              // 2,359,296 f
  float* rs  = yt + 2359296;                       // 7,962,624 f

  prep_ytr_kernel<<<1296, 256, 0, stream>>>(w_om, w_dc, y, ap2, ap1, yt);
  conv_mfma_kernel<<<1152, 256, 0, stream>>>(x, ap2, b_om, om);
  resize_kernel<<<1152, 256, 0, stream>>>(om, rs);
  deform_mfma_kernel<<<2304, 256, 0, stream>>>(yt, rs, ap1, b_dc, out);
}

// Round 13
// 75.827 us; speedup vs baseline: 1.1652x; 1.0619x over previous
//
#include <hip/hip_runtime.h>
#include <math.h>

#define HX 48
#define WX 48
#define OMC 216
#define HY 96
#define WY 96

typedef __attribute__((ext_vector_type(8))) short bf16x8;
typedef __attribute__((ext_vector_type(4))) float f32x4;

__device__ inline unsigned short f2bf(float f) {
  unsigned u = __float_as_uint(f);
  return (unsigned short)((u + 0x7fffu + ((u >> 16) & 1u)) >> 16);  // RNE
}
__device__ inline unsigned pk2(float a, float b) {
  return (unsigned)f2bf(a) | ((unsigned)f2bf(b) << 16);
}

// ws layout (floats):
//  om  @ 0          : 1,990,656
//  ap2 @ 1,990,656  :    73,728   (147,456 bf16)
//  ap1 @ 2,064,384  :    18,432   ( 36,864 bf16)
//  yt  @ 2,082,816  : 2,359,296
//  (rs buffer eliminated — resize fused into deform)

// ---------- fused: prep (blocks 0..719) + ytr (blocks 720..1295) ----------
__global__ __launch_bounds__(256) void prep_ytr_kernel(
    const float* __restrict__ w_om, const float* __restrict__ w_dc,
    const float* __restrict__ y,
    unsigned short* __restrict__ ap2, unsigned short* __restrict__ ap1,
    float* __restrict__ yt) {
  __shared__ float tile[64][65];
  int bid = blockIdx.x;
  int t = threadIdx.x;
  if (bid < 720) {
    int idx = bid * 256 + t;                  // 0..184319
    if (idx < 147456) {
      int j = idx & 7;
      int tmp = idx >> 3;
      int l = tmp & 63; tmp >>= 6;
      int m = tmp & 15; tmp >>= 4;            // 0..17
      int s = tmp % 6, p = tmp / 6;
      int oc = m * 16 + (l & 15);
      int kk = s * 32 + (l >> 4) * 8 + j;     // 0..191
      int tap = kk >> 6, c = kk & 63;
      int k = p * 3 + tap;
      ap2[idx] = (oc < OMC) ? f2bf(w_om[oc * 576 + c * 9 + k]) : (unsigned short)0;
    } else {
      int i2 = idx - 147456;                  // < 36864
      int j = i2 & 7;
      int tmp = i2 >> 3;
      int l = tmp & 63; tmp >>= 6;
      int w = tmp & 3; tmp >>= 2;             // 0..17
      int s = tmp % 6, p = tmp / 6;
      int oc = w * 16 + (l & 15);
      int kk = s * 32 + (l >> 4) * 8 + j;
      int tap = kk >> 6, c = kk & 63;
      ap1[i2] = f2bf(w_dc[oc * 576 + c * 9 + p * 3 + tap]);
    }
  } else {
    int blk = bid - 720;                      // 576 = 4b * 144
    int b = blk / 144;
    int p0 = (blk % 144) * 64;
    int pl = t & 63;
    int cb = t >> 6;
#pragma unroll
    for (int i = 0; i < 16; ++i) {
      int c = cb * 16 + i;
      tile[c][pl] = y[((size_t)(b * 64 + c)) * 9216 + p0 + pl];
    }
    __syncthreads();
    int cw = t & 63;
    int pb = t >> 6;
#pragma unroll
    for (int i = 0; i < 16; ++i) {
      int p = pb * 16 + i;
      yt[((size_t)(b * 9216 + p0 + p)) * 64 + cw] = tile[cw][p];
    }
  }
}

// ---------- conv (9 taps) via MFMA, oc-split: 128oc x 16px per block ----------
__global__ __launch_bounds__(256) void conv_mfma_kernel(
    const float* __restrict__ x, const unsigned short* __restrict__ ap2,
    const float* __restrict__ bom, float* __restrict__ om) {
  __shared__ unsigned short sB[9][16][72];    // 20736 B, [tap][px][c]
  int t = threadIdx.x;
  int bid = blockIdx.x;                       // 1152
  int logical = (bid & 7) * 144 + (bid >> 3); // bijective XCD swizzle
  int och = logical / 576;                    // oc half
  int rem = logical % 576;
  int b = rem / 144;
  int tl = rem % 144;
  int h0 = (tl / 12) * 4;
  int w0 = (tl % 12) * 4;
  int s_ic = t >> 2;
  int s_row = t & 3;
  const float* xp = x + (size_t)b * 64 * 2304 + (size_t)s_ic * 2304;

#pragma unroll
  for (int k = 0; k < 9; ++k) {
    int dy = k / 3 - 1, dx = k % 3 - 1;
    int hh = h0 + s_row + dy;
    int ww = w0 + dx;
    bool hv = (unsigned)hh < (unsigned)HX;
    int hc = min(max(hh, 0), HX - 1);
    const float* xr = xp + hc * WX;
#pragma unroll
    for (int j = 0; j < 4; ++j) {
      int wcj = min(max(ww + j, 0), WX - 1);
      float v = xr[wcj] * ((hv && (unsigned)(ww + j) < (unsigned)WX) ? 1.f : 0.f);
      sB[k][s_row * 4 + j][s_ic] = f2bf(v);
    }
  }
  __syncthreads();

  int w = t >> 6;
  int l = t & 63;
  int lr = l & 15;
  int lg = l >> 4;
  f32x4 acc[2] = {};
#pragma unroll
  for (int p = 0; p < 3; ++p) {
#pragma unroll
    for (int s = 0; s < 6; ++s) {
      int tapidx = p * 3 + (s >> 1);
      int c0 = (s & 1) * 32;
      bf16x8 bv = *(const bf16x8*)&sB[tapidx][lr][c0 + lg * 8];
#pragma unroll
      for (int m = 0; m < 2; ++m) {
        int mq = och * 8 + w * 2 + m;         // 0..15
        bf16x8 av = *(const bf16x8*)(ap2 +
            (size_t)((((p * 6 + s) * 16) + mq) * 64 + l) * 8);
        acc[m] = __builtin_amdgcn_mfma_f32_16x16x32_bf16(av, bv, acc[m], 0, 0, 0);
      }
    }
  }
  int prow = lr >> 2, pcol = lr & 3;
#pragma unroll
  for (int m = 0; m < 2; ++m) {
    int ocb = (och * 8 + w * 2 + m) * 16 + lg * 4;
    if (ocb < OMC) {
      float4 bb = *(const float4*)&bom[ocb];
      float bvv[4] = {bb.x, bb.y, bb.z, bb.w};
#pragma unroll
      for (int i = 0; i < 4; ++i) {
        om[((size_t)(b * OMC + ocb + i)) * 2304 + (h0 + prow) * WX + w0 + pcol] =
            acc[m][i] + bvv[i];
      }
    }
  }
}

// ---------- deform: fused resize + gather + MFMA, 16px x 64oc per block ----------
// NOTE: 3rd macro param must NOT be named w/x/y/z/s/d — member-access capture!
#define MAD4(d, s, mw)                                                  \
  d.x += (mw) * s.x; d.y += (mw) * s.y; d.z += (mw) * s.z; d.w += (mw) * s.w;

__global__ __launch_bounds__(256) void deform_mfma_kernel(
    const float* __restrict__ yt, const float* __restrict__ om,
    const unsigned short* __restrict__ ap1, const float* __restrict__ bdc,
    float* __restrict__ out) {
  __shared__ float sOm[OMC][16];                // 13824 B: [ch][r*4+c] 4x4 src tile
  __shared__ unsigned short sval[2][16][72];    // 4608 B
  int t = threadIdx.x;
  int bid = blockIdx.x;                         // 2304
  int logical = (bid & 7) * 288 + (bid >> 3);   // bijective XCD swizzle
  int b = logical / 576;
  int tl = logical % 576;
  int h0 = (tl / 24) * 4;                       // 24 h-tiles of 4
  int w0 = (tl % 24) * 4;                       // 24 w-tiles of 4
  int rowbase = h0 / 2 - 1;
  int colbase = w0 / 2 - 1;
  const float* omb = om + (size_t)b * OMC * 2304;

  // stage the 4x4 source region of all 216 om channels (clamped replication)
  for (int i = t; i < OMC * 16; i += 256) {
    int ch = i >> 4;
    int r = (i >> 2) & 3, c = i & 3;
    int sr = min(max(rowbase + r, 0), HX - 1);
    int sc = min(max(colbase + c, 0), WX - 1);
    sOm[ch][(r << 2) | c] = omb[(size_t)ch * 2304 + sr * WX + sc];
  }

  int item = t >> 1;                            // 0..127 = g*16 + px
  int g = item >> 4;
  int px = item & 15;
  int cp = t & 1;                               // channel half of the 8-ch group
  int gh = h0 + (px >> 2);
  int gw = w0 + (px & 3);
  int chb = g * 8 + cp * 4;
  const float* ytb = yt + (size_t)b * 9216 * 64;

  // tap-invariant bilinear-resize coeffs for (gh,gw)
  float sh = fmaxf(gh * 0.5f - 0.25f, 0.f);
  float swc = fmaxf(gw * 0.5f - 0.25f, 0.f);
  int i0h = (int)sh; float th = sh - (float)i0h;
  int i0w = (int)swc; float tw = swc - (float)i0w;
  int li = i0h - rowbase;                       // in [0,2]
  int lj = i0w - colbase;                       // in [0,2]
  float r00 = (1.f - th) * (1.f - tw), r01 = (1.f - th) * tw;
  float r10 = th * (1.f - tw),         r11 = th * tw;
  int a00 = (li << 2) | lj, a01 = a00 + 1, a10 = a00 + 4, a11 = a00 + 5;

  int w = t >> 6;
  int l = t & 63;
  int lr = l & 15;
  int lg = l >> 4;

  __syncthreads();                              // sOm ready

  float4 C[2][4];     // corner loads, slot tap&1
  float W[2][4];      // corner weights, slot tap&1

  auto triple = [&](int k, float* T) {          // resize-on-the-fly (from LDS)
    int cy = g * 18 + k * 2;
    int cm = 144 + g * 9 + k;
    float oy = r00 * sOm[cy][a00] + r01 * sOm[cy][a01] +
               r10 * sOm[cy][a10] + r11 * sOm[cy][a11];
    float ox = r00 * sOm[cy + 1][a00] + r01 * sOm[cy + 1][a01] +
               r10 * sOm[cy + 1][a10] + r11 * sOm[cy + 1][a11];
    float mv = r00 * sOm[cm][a00] + r01 * sOm[cm][a01] +
               r10 * sOm[cm][a10] + r11 * sOm[cm][a11];
    T[0] = (float)(gh + k / 3 - 1) + oy;
    T[1] = (float)(gw + k % 3 - 1) + ox;
    T[2] = 1.f / (1.f + __expf(-mv));
  };
  auto issueC = [&](const float* Ri, float4* Co, float* Wo) {
    float py = Ri[0], pxf = Ri[1], m = Ri[2];
    float y0f = floorf(py), x0f = floorf(pxf);
    float ty = py - y0f, tx = pxf - x0f;
    int y0 = (int)y0f, x0 = (int)x0f;
    int y1 = y0 + 1, x1 = x0 + 1;
    float w00 = (1.f - ty) * (1.f - tx) * m, w01 = (1.f - ty) * tx * m;
    float w10 = ty * (1.f - tx) * m,         w11 = ty * tx * m;
    Wo[0] = ((unsigned)y0 < HY && (unsigned)x0 < WY) ? w00 : 0.f;
    Wo[1] = ((unsigned)y0 < HY && (unsigned)x1 < WY) ? w01 : 0.f;
    Wo[2] = ((unsigned)y1 < HY && (unsigned)x0 < WY) ? w10 : 0.f;
    Wo[3] = ((unsigned)y1 < HY && (unsigned)x1 < WY) ? w11 : 0.f;
    int y0c = min(max(y0, 0), HY - 1), y1c = min(max(y1, 0), HY - 1);
    int x0c = min(max(x0, 0), WY - 1), x1c = min(max(x1, 0), WY - 1);
    Co[0] = *(const float4*)(ytb + (size_t)(y0c * WY + x0c) * 64 + chb);
    Co[1] = *(const float4*)(ytb + (size_t)(y0c * WY + x1c) * 64 + chb);
    Co[2] = *(const float4*)(ytb + (size_t)(y1c * WY + x0c) * 64 + chb);
    Co[3] = *(const float4*)(ytb + (size_t)(y1c * WY + x1c) * 64 + chb);
  };
  auto finishC = [&](const float4* Ci, const float* Wi, int buf) {
    float4 s0 = {0, 0, 0, 0};
    MAD4(s0, Ci[0], Wi[0]) MAD4(s0, Ci[1], Wi[1])
    MAD4(s0, Ci[2], Wi[2]) MAD4(s0, Ci[3], Wi[3])
    *(uint2*)&sval[buf][px][chb] = make_uint2(pk2(s0.x, s0.y), pk2(s0.z, s0.w));
  };

  // prologue: tap 0 corner loads in flight
  {
    float T0[3];
    triple(0, T0);
    issueC(T0, C[0], W[0]);
  }

  f32x4 acc = {};
#pragma unroll
  for (int tp = 0; tp < 9; ++tp) {
    if (tp + 1 < 9) {                            // next tap: 1-iter flight
      float Tn[3];
      triple(tp + 1, Tn);
      issueC(Tn, C[(tp + 1) & 1], W[(tp + 1) & 1]);
    }
    finishC(C[tp & 1], W[tp & 1], tp & 1);       // issued last iter
    __syncthreads();
    int p = tp / 3;
    int sl = (tp % 3) * 2;
#pragma unroll
    for (int half = 0; half < 2; ++half) {
      int s = sl + half;
      bf16x8 av = *(const bf16x8*)(ap1 +
          (size_t)(((p * 6 + s) * 4 + w) * 64 + l) * 8);
      bf16x8 bv = *(const bf16x8*)&sval[tp & 1][lr][half * 32 + lg * 8];
      acc = __builtin_amdgcn_mfma_f32_16x16x32_bf16(av, bv, acc, 0, 0, 0);
    }
    // finishC[tp+2] (same buf) is fenced by barrier[tp+1] which program-order
    // follows this MFMA's LDS reads on every wave.
  }

  // epilogue: bias + relu + store (oc = w*16+lg*4+i, px = lr in 4x4 tile)
  float4 bb = *(const float4*)&bdc[w * 16 + lg * 4];
  float bvv[4] = {bb.x, bb.y, bb.z, bb.w};
#pragma unroll
  for (int i = 0; i < 4; ++i) {
    int oc = w * 16 + lg * 4 + i;
    out[((size_t)(b * 64 + oc) * 96 + h0 + (lr >> 2)) * 96 + w0 + (lr & 3)] =
        fmaxf(acc[i] + bvv[i], 0.f);
  }
}

extern "C" void kernel_launch(void* const* d_in, const int* in_sizes, int n_in,
                              void* d_out, int out_size, void* d_ws, size_t ws_size,
                              hipStream_t stream) {
  const float* x = (const float*)d_in[0];
  const float* y = (const float*)d_in[1];
  const float* w_om = (const float*)d_in[2];
  const float* b_om = (const float*)d_in[3];
  const float* w_dc = (const float*)d_in[4];
  const float* b_dc = (const float*)d_in[5];
  float* out = (float*)d_out;

  float* om  = (float*)d_ws;                       // 1,990,656 f
  unsigned short* ap2 = (unsigned short*)(om + 1990656);   // 147,456 bf16
  unsigned short* ap1 = ap2 + 147456;              //  36,864 bf16
  float* yt  = (float*)(ap1 + 36864);              // 2,359,296 f

  prep_ytr_kernel<<<1296, 256, 0, stream>>>(w_om, w_dc, y, ap2, ap1, yt);
  conv_mfma_kernel<<<1152, 256, 0, stream>>>(x, ap2, b_om, om);
  deform_mfma_kernel<<<2304, 256, 0, stream>>>(yt, om, ap1, b_dc, out);
}